// Round 11
// baseline (1006.392 us; speedup 1.0000x reference)
//
#include <hip/hip_runtime.h>

typedef unsigned short u16;
using bf16x8 = __attribute__((ext_vector_type(8))) __bf16;
using f32x4  = __attribute__((ext_vector_type(4))) float;
using u16x4  = __attribute__((ext_vector_type(4))) unsigned short;

#define D_DIM 1024
#define F_DIM 4096

// ---------------- Cayley table (Cl(3,0)), compile-time ----------------
struct Cayley { int k[8][8]; int s[8][8]; };
constexpr Cayley make_cayley() {
    Cayley c{};
    const int gens[8][3] = {{0,0,0},{1,0,0},{2,0,0},{3,0,0},{1,2,0},{1,3,0},{2,3,0},{1,2,3}};
    const int glen[8] = {0,1,1,1,2,2,2,3};
    const int mask2idx[8] = {0,1,2,4,3,5,6,7};
    for (int i = 0; i < 8; ++i) {
        for (int j = 0; j < 8; ++j) {
            int g[6] = {0,0,0,0,0,0};
            int n = 0;
            for (int t = 0; t < glen[i]; ++t) g[n++] = gens[i][t];
            for (int t = 0; t < glen[j]; ++t) g[n++] = gens[j][t];
            int sign = 1;
            bool changed = true;
            while (changed) {
                changed = false;
                int t = 0;
                while (t + 1 < n) {
                    if (g[t] == g[t+1]) {
                        for (int u = t; u + 2 < n; ++u) g[u] = g[u+2];
                        n -= 2; changed = true;
                        if (t > 0) --t;
                    } else if (g[t] > g[t+1]) {
                        int tmp = g[t]; g[t] = g[t+1]; g[t+1] = tmp;
                        sign = -sign; changed = true; ++t;
                    } else {
                        ++t;
                    }
                }
            }
            int mask = 0;
            for (int t = 0; t < n; ++t) mask |= 1 << (g[t] - 1);
            c.k[i][j] = mask2idx[mask];
            c.s[i][j] = sign;
        }
    }
    return c;
}
constexpr Cayley CAY = make_cayley();

// ---------------- helpers ----------------
__device__ __forceinline__ u16 f2bf(float f) {           // RNE f32->bf16
    unsigned u = __float_as_uint(f);
    unsigned r = 0x7FFFu + ((u >> 16) & 1u);
    return (u16)((u + r) >> 16);
}

__device__ __forceinline__ void gload16(const u16* g, const u16* l) {
    __builtin_amdgcn_global_load_lds(
        (const __attribute__((address_space(1))) void*)g,
        (__attribute__((address_space(3))) void*)l, 16, 0, 0);
}

// swizzled LDS fragment read: tile is [256][64] u16, row-linear with slot^=(row&7)
__device__ __forceinline__ bf16x8 frag(const u16* tile, int row, int ks, int lane) {
    const int slot = ((ks << 2) + (lane >> 4)) ^ (lane & 7);
    return *(const bf16x8*)(tile + row * 64 + slot * 8);
}

// stage one 128x64 half-tile (2 gload16/thread), source pre-swizzled
__device__ __forceinline__ void stage_half(
    const u16* __restrict__ G, int baseRow, int kt, u16* ldsHalf,
    int wave, int sr, int sslot, int KD)
{
    #pragma unroll
    for (int q = 0; q < 2; ++q) {
        const int idx_w = q*512 + wave*64;
        const int row = (idx_w >> 3) + sr;
        gload16(G + (size_t)(baseRow + row)*KD + kt*64 + sslot*8, ldsHalf + idx_w*8);
    }
}

__device__ __forceinline__ void rdA(bf16x8 (&af)[4][2], const u16* T, int base, int fr, int lane) {
    #pragma unroll
    for (int m = 0; m < 4; ++m)
        #pragma unroll
        for (int ks = 0; ks < 2; ++ks)
            af[m][ks] = frag(T, base + m*16 + fr, ks, lane);
}

__device__ __forceinline__ void rdB(bf16x8 (&bf)[2][2], const u16* T, int base, int fr, int lane) {
    #pragma unroll
    for (int n = 0; n < 2; ++n)
        #pragma unroll
        for (int ks = 0; ks < 2; ++ks)
            bf[n][ks] = frag(T, base + n*16 + fr, ks, lane);
}

__device__ __forceinline__ void mm16(f32x4 (&acc)[8][4], int mo, int no,
                                     bf16x8 (&af)[4][2], bf16x8 (&bf)[2][2]) {
    __builtin_amdgcn_s_setprio(1);
    #pragma unroll
    for (int m = 0; m < 4; ++m)
        #pragma unroll
        for (int n = 0; n < 2; ++n)
            #pragma unroll
            for (int ks = 0; ks < 2; ++ks)
                acc[mo+m][no+n] = __builtin_amdgcn_mfma_f32_16x16x32_bf16(af[m][ks], bf[n][ks], acc[mo+m][no+n], 0, 0, 0);
    __builtin_amdgcn_s_setprio(0);
}

#define BAR()  __builtin_amdgcn_s_barrier()
#define SB0()  __builtin_amdgcn_sched_barrier(0)
#define LG0()  do { asm volatile("s_waitcnt lgkmcnt(0)" ::: "memory"); SB0(); } while (0)
#define VM(N)  asm volatile("s_waitcnt vmcnt(" #N ")" ::: "memory")

// ---------------- weight transpose f32 [R][C] -> bf16 [C][R], with optional
// gate/up chunk interleave: mode 0 plain, 1 gate (16-col chunks even), 2 up (odd) ----
__global__ __launch_bounds__(256) void transpose_kernel(
    const float* __restrict__ in, u16* __restrict__ outp, int R, int C, int mode)
{
    __shared__ float tile[32][33];
    const int tx = threadIdx.x & 31, ty = threadIdx.x >> 5;
    const int c0 = blockIdx.x * 32, r0 = blockIdx.y * 32;
    #pragma unroll
    for (int t = 0; t < 4; ++t)
        tile[ty + t*8][tx] = in[(size_t)(r0 + ty + t*8) * C + c0 + tx];
    __syncthreads();
    #pragma unroll
    for (int t = 0; t < 4; ++t) {
        const int c = c0 + ty + t*8;
        int orow;
        if (mode == 0)      orow = c;
        else if (mode == 1) orow = ((c >> 4) << 5) + (c & 15);
        else                orow = ((c >> 4) << 5) + 16 + (c & 15);
        outp[(size_t)orow * R + r0 + tx] = f2bf(tile[tx][ty + t*8]);
    }
}

// ---------------- fused geometric product + mix + LayerNorm -> bf16 flat ----------------
__global__ __launch_bounds__(256, 2) void geo_ln_kernel(
    const float* __restrict__ x, const float* __restrict__ iw,
    const float* __restrict__ gg, const float* __restrict__ lnw,
    const float* __restrict__ lnb, u16* __restrict__ flat)
{
    __shared__ float wsig[64];
    __shared__ float red[4][16];
    const int tid = threadIdx.x;
    if (tid < 64) wsig[tid] = 1.f / (1.f + __expf(-iw[tid]));
    __syncthreads();
    const float g   = 1.f / (1.f + __expf(-gg[0]));
    const float gm1 = 1.f - g;

    float coef[64];
    #pragma unroll
    for (int t = 0; t < 64; ++t) coef[t] = (float)CAY.s[t >> 3][t & 7] * wsig[t];

    const int n  = blockIdx.x;
    const int d0 = tid * 4;
    const float* xb = x + (size_t)n * 8 * D_DIM;
    f32x4 xv[8];
    #pragma unroll
    for (int i = 0; i < 8; ++i) xv[i] = __builtin_nontemporal_load((const f32x4*)(xb + i * D_DIM + d0));

    float mix[8][4];
    #pragma unroll
    for (int s4 = 0; s4 < 4; ++s4) {
        float xs[8];
        #pragma unroll
        for (int i = 0; i < 8; ++i) xs[i] = xv[i][s4];
        float geo[8] = {0.f,0.f,0.f,0.f,0.f,0.f,0.f,0.f};
        #pragma unroll
        for (int i = 0; i < 8; ++i) {
            #pragma unroll
            for (int j = 0; j < 8; ++j) {
                geo[CAY.k[i][j]] = fmaf(coef[i*8+j] * xs[i], xs[j], geo[CAY.k[i][j]]);
            }
        }
        #pragma unroll
        for (int k = 0; k < 8; ++k) mix[k][s4] = g * geo[k] + gm1 * xs[k];
    }

    float s1[8], s2[8];
    #pragma unroll
    for (int k = 0; k < 8; ++k) {
        s1[k] = 0.f; s2[k] = 0.f;
        #pragma unroll
        for (int s4 = 0; s4 < 4; ++s4) {
            s1[k] += mix[k][s4];
            s2[k]  = fmaf(mix[k][s4], mix[k][s4], s2[k]);
        }
    }
    #pragma unroll
    for (int m = 1; m < 64; m <<= 1) {
        #pragma unroll
        for (int k = 0; k < 8; ++k) {
            s1[k] += __shfl_xor(s1[k], m, 64);
            s2[k] += __shfl_xor(s2[k], m, 64);
        }
    }
    const int wave = tid >> 6, lane = tid & 63;
    if (lane == 0) {
        #pragma unroll
        for (int k = 0; k < 8; ++k) { red[wave][k] = s1[k]; red[wave][8+k] = s2[k]; }
    }
    __syncthreads();
    float mean[8], rstd[8];
    #pragma unroll
    for (int k = 0; k < 8; ++k) {
        float a = red[0][k] + red[1][k] + red[2][k] + red[3][k];
        float b = red[0][8+k] + red[1][8+k] + red[2][8+k] + red[3][8+k];
        float mu  = a * (1.f / 1024.f);
        float var = b * (1.f / 1024.f) - mu * mu;
        mean[k] = mu;
        rstd[k] = rsqrtf(var + 1e-5f);
    }
    f32x4 lw = *(const f32x4*)(lnw + d0);
    f32x4 lb = *(const f32x4*)(lnb + d0);
    #pragma unroll
    for (int k = 0; k < 8; ++k) {
        u16x4 o;
        #pragma unroll
        for (int s4 = 0; s4 < 4; ++s4) {
            float v = (mix[k][s4] - mean[k]) * rstd[k] * lw[s4] + lb[s4];
            o[s4] = f2bf(v);
        }
        *(u16x4*)(flat + ((size_t)(n * 8 + k)) * D_DIM + d0) = o;
    }
}

// ================= 256x256 8-wave GEMM, faithful m201 8-phase / 2 K-tiles =================
// A [M][KDIM] bf16, B [N][KDIM] bf16 (B^T). EPI=1: swiglu-pack -> h bf16 (nt).
// EPI=0: out = X + acc, f32 (nt).
// Iteration i: K-tiles ta=2i (buf0), tb=2i+1 (buf1); na=2i+2, nb=2i+3.
// ONE half-tile staged per phase, TWO vmcnt waits per iteration (ph4/ph8 only),
// 4-7 phases of prefetch lead:
//   stages: ph1:B-H1(tb)  ph2:A-H0(na)  ph3:B-H0(na)  ph4:A-H1(na)
//           ph5:B-H1(na)  ph6:A-H0(nb)  ph7:B-H0(nb)  ph8:A-H1(nb)
//   ph4-end vmcnt(6): keeps ph2-4's 3 halves -> retires ALL of tb (staged
//                     ph6(i-1),ph7(i-1),ph8(i-1),ph1(i)) before ph5-7 read it.
//   ph8-end vmcnt(6): keeps ph6-8's 3 halves -> retires ALL of na (staged
//                     ph2-ph5) before ph1-3 of i+1 read it.
// Write-hazards: every stage targets a region whose last ds_read completed
// >=1 dual-barrier earlier, and no read of the region occurs inside the
// [issue, forcing-vmcnt] retire window (audited per phase).
// Prologue: tile0 x4 halves, tile1 x{A-H0,B-H0,A-H1} (14 loads), vmcnt(6)
// retires exactly tile0. LAST iter: skip ph2-8 stages; ph4->vmcnt(0); ph8 none.
// Each phase: {reads; stage; [lgkmcnt(8) if 12 reads]; BAR; lgkmcnt(0)+SB0;
//              setprio(1) 16xMFMA setprio(0); [vmcnt]; BAR; SB0}.
template<int KDIM, bool LAST>
__device__ __forceinline__ void iter8(
    int i, const u16* __restrict__ A, const u16* __restrict__ B,
    u16 (*As)[256][64], u16 (*Bs)[256][64],
    int brow, int bcol, int wave, int lane, int wm, int wn, int fr,
    f32x4 (&acc)[8][4])
{
    const int tb = 2*i + 1, na = 2*i + 2, nb = 2*i + 3;
    const u16* At0 = &As[0][0][0];
    const u16* Bt0 = &Bs[0][0][0];
    const u16* At1 = &As[1][0][0];
    const u16* Bt1 = &Bs[1][0][0];
    const int sr = lane >> 3, sslot = (lane & 7) ^ sr;

    bf16x8 af[4][2], bf0[2][2], bf1[2][2];

    // ===== ph1: quadrant (0,0) of ta ===== reads A-H0(ta), B-H0(ta)
    rdA(af, At0, wm*64, fr, lane);
    rdB(bf0, Bt0, wn*32, fr, lane);
    stage_half(B, bcol+128, tb, &Bs[1][128][0], wave, sr, sslot, KDIM);      // B-H1(tb)
    asm volatile("s_waitcnt lgkmcnt(8)" ::: "memory");
    BAR(); LG0();
    mm16(acc, 0, 0, af, bf0);
    BAR(); SB0();

    // ===== ph2: quadrant (0,1) of ta ===== reads B-H1(ta)
    rdB(bf1, Bt0, 128 + wn*32, fr, lane);
    if (!LAST) stage_half(A, brow, na, &As[0][0][0], wave, sr, sslot, KDIM); // A-H0(na)
    BAR(); LG0();
    mm16(acc, 0, 2, af, bf1);
    BAR(); SB0();

    // ===== ph3: quadrant (1,0) of ta ===== reads A-H1(ta)
    rdA(af, At0, 128 + wm*64, fr, lane);
    if (!LAST) stage_half(B, bcol, na, &Bs[0][0][0], wave, sr, sslot, KDIM); // B-H0(na)
    BAR(); LG0();
    mm16(acc, 4, 0, af, bf0);
    BAR(); SB0();

    // ===== ph4: quadrant (1,1) of ta ===== no reads
    if (!LAST) stage_half(A, brow+128, na, &As[0][128][0], wave, sr, sslot, KDIM); // A-H1(na)
    BAR(); SB0();
    mm16(acc, 4, 2, af, bf1);
    if (LAST) VM(0); else VM(6);
    BAR(); SB0();

    // ===== ph5: quadrant (0,0) of tb ===== reads A-H0(tb), B-H0(tb)
    rdA(af, At1, wm*64, fr, lane);
    rdB(bf0, Bt1, wn*32, fr, lane);
    if (!LAST) stage_half(B, bcol+128, na, &Bs[0][128][0], wave, sr, sslot, KDIM); // B-H1(na)
    asm volatile("s_waitcnt lgkmcnt(8)" ::: "memory");
    BAR(); LG0();
    mm16(acc, 0, 0, af, bf0);
    BAR(); SB0();

    // ===== ph6: quadrant (0,1) of tb ===== reads B-H1(tb)
    rdB(bf1, Bt1, 128 + wn*32, fr, lane);
    if (!LAST) stage_half(A, brow, nb, &As[1][0][0], wave, sr, sslot, KDIM); // A-H0(nb)
    BAR(); LG0();
    mm16(acc, 0, 2, af, bf1);
    BAR(); SB0();

    // ===== ph7: quadrant (1,0) of tb ===== reads A-H1(tb)
    rdA(af, At1, 128 + wm*64, fr, lane);
    if (!LAST) stage_half(B, bcol, nb, &Bs[1][0][0], wave, sr, sslot, KDIM); // B-H0(nb)
    BAR(); LG0();
    mm16(acc, 4, 0, af, bf0);
    BAR(); SB0();

    // ===== ph8: quadrant (1,1) of tb ===== no reads
    if (!LAST) stage_half(A, brow+128, nb, &As[1][128][0], wave, sr, sslot, KDIM); // A-H1(nb)
    BAR(); SB0();
    mm16(acc, 4, 2, af, bf1);
    if (!LAST) VM(6);
    BAR(); SB0();
}

template<int KDIM, int EPI>
__global__ __launch_bounds__(512, 2) void gemm8ph(
    const u16* __restrict__ A, const u16* __restrict__ B,
    const float* __restrict__ X, void* __restrict__ OUT, int Ncols)
{
    constexpr int NT = KDIM / 64;
    constexpr int NI = NT / 2;
    static_assert(NT % 2 == 0, "NT must be even");
    __shared__ alignas(16) u16 As[2][256][64];
    __shared__ alignas(16) u16 Bs[2][256][64];

    const int nbx = Ncols >> 8;
    const int nwg = gridDim.x;
    const int bid = blockIdx.x;
    int brow, bcol;
    if constexpr (EPI == 1) {
        // XCD column-strip (round-5 best for GEMM1): each XCD owns nbx/8 cols;
        // its B strip stays L2-resident.
        const int xcd = bid & 7, idx = bid >> 3;
        const int cpx = nbx >> 3;
        bcol = (xcd * cpx + (idx & (cpx - 1))) << 8;
        brow = (idx / cpx) << 8;
    } else {
        // standard XCD swizzle (round-4 best for GEMM2)
        const int wg = (bid & 7) * (nwg >> 3) + (bid >> 3);
        brow = (wg / nbx) << 8;
        bcol = (wg % nbx) << 8;
    }

    const int tid = threadIdx.x;
    const int wave = tid >> 6, lane = tid & 63;
    const int wm = wave >> 2, wn = wave & 3;
    const int fr = lane & 15, fq = lane >> 4;
    const int sr = lane >> 3, sslot = (lane & 7) ^ sr;

    f32x4 acc[8][4];
    #pragma unroll
    for (int i = 0; i < 8; ++i)
        #pragma unroll
        for (int j = 0; j < 4; ++j) acc[i][j] = {0.f, 0.f, 0.f, 0.f};

    // ---- prologue: tile0 (4 halves) + tile1 (A-H0, B-H0, A-H1) ----
    stage_half(A, brow,     0, &As[0][0][0],   wave, sr, sslot, KDIM);
    stage_half(B, bcol,     0, &Bs[0][0][0],   wave, sr, sslot, KDIM);
    stage_half(A, brow+128, 0, &As[0][128][0], wave, sr, sslot, KDIM);
    stage_half(B, bcol+128, 0, &Bs[0][128][0], wave, sr, sslot, KDIM);
    stage_half(A, brow,     1, &As[1][0][0],   wave, sr, sslot, KDIM);
    stage_half(B, bcol,     1, &Bs[1][0][0],   wave, sr, sslot, KDIM);
    stage_half(A, brow+128, 1, &As[1][128][0], wave, sr, sslot, KDIM);
    VM(6);            // 14 issued; retire 8 oldest = tile0 complete
    BAR(); SB0();

    // ---- main loop ----
    #pragma unroll 1
    for (int i = 0; i < NI - 1; ++i)
        iter8<KDIM, false>(i, A, B, As, Bs, brow, bcol, wave, lane, wm, wn, fr, acc);
    iter8<KDIM, true>(NI - 1, A, B, As, Bs, brow, bcol, wave, lane, wm, wn, fr, acc);

    // ---- epilogue (nontemporal stream-out) ----
    if constexpr (EPI == 1) {
        u16* H = (u16*)OUT;
        const int Nh = Ncols >> 1;
        #pragma unroll
        for (int qm = 0; qm < 2; ++qm)
            #pragma unroll
            for (int m = 0; m < 4; ++m) {
                const int row = brow + qm*128 + wm*64 + m*16 + fq*4;
                #pragma unroll
                for (int qn = 0; qn < 2; ++qn) {
                    const int col = (bcol >> 1) + qn*64 + wn*16 + fr;
                    f32x4 g = acc[qm*4+m][qn*2+0];
                    f32x4 u = acc[qm*4+m][qn*2+1];
                    #pragma unroll
                    for (int r = 0; r < 4; ++r) {
                        float gv = g[r], uv = u[r];
                        float hv = (gv / (1.f + __expf(-gv))) * uv;
                        __builtin_nontemporal_store(f2bf(hv), &H[(size_t)(row + r) * Nh + col]);
                    }
                }
            }
    } else {
        float* Of = (float*)OUT;
        #pragma unroll
        for (int mi = 0; mi < 8; ++mi) {
            const int row = brow + (mi>>2)*128 + wm*64 + (mi&3)*16 + fq*4;
            #pragma unroll
            for (int ni = 0; ni < 4; ++ni) {
                const int col = bcol + (ni>>1)*128 + wn*32 + (ni&1)*16 + fr;
                #pragma unroll
                for (int r = 0; r < 4; ++r) {
                    float xv = __builtin_nontemporal_load(&X[(size_t)(row+r)*Ncols + col]);
                    __builtin_nontemporal_store(xv + acc[mi][ni][r], &Of[(size_t)(row+r)*Ncols + col]);
                }
            }
        }
    }
}

// ---------------- launch ----------------
extern "C" void kernel_launch(void* const* d_in, const int* in_sizes, int n_in,
                              void* d_out, int out_size, void* d_ws, size_t ws_size,
                              hipStream_t stream) {
    const float* x     = (const float*)d_in[0];
    const float* iw    = (const float*)d_in[1];
    const float* gg    = (const float*)d_in[2];
    const float* lnw   = (const float*)d_in[3];
    const float* lnb   = (const float*)d_in[4];
    const float* wgate = (const float*)d_in[5];
    const float* wup   = (const float*)d_in[6];
    const float* wdown = (const float*)d_in[7];
    float* out = (float*)d_out;

    const int ntok = in_sizes[0] / (8 * D_DIM);   // 4096
    const int M    = ntok * 8;                    // 32768

    const size_t flat_b = (size_t)M * D_DIM * 2;          //  64 MiB
    const size_t wc_b   = (size_t)2 * D_DIM * F_DIM * 2;  //  16 MiB (combined gate+up)
    const size_t wd_b   = (size_t)D_DIM * F_DIM * 2;      //   8 MiB
    const size_t h_b    = (size_t)M * F_DIM * 2;          // 256 MiB
    const size_t need   = flat_b + wc_b + wd_b + h_b;
    if (ws_size < need) return;

    char* ws = (char*)d_ws;
    u16* flat = (u16*)(ws);
    u16* wc   = (u16*)(ws + flat_b);
    u16* wdt  = (u16*)(ws + flat_b + wc_b);
    u16* h    = (u16*)(ws + flat_b + wc_b + wd_b);

    transpose_kernel<<<dim3(F_DIM/32, D_DIM/32), 256, 0, stream>>>(wgate, wc,  D_DIM, F_DIM, 1);
    transpose_kernel<<<dim3(F_DIM/32, D_DIM/32), 256, 0, stream>>>(wup,   wc,  D_DIM, F_DIM, 2);
    transpose_kernel<<<dim3(D_DIM/32, F_DIM/32), 256, 0, stream>>>(wdown, wdt, F_DIM, D_DIM, 0);
    geo_ln_kernel<<<dim3(ntok), 256, 0, stream>>>(x, iw, gg, lnw, lnb, flat);

    // GEMM1: [32768][1024] x [8192][1024]^T -> swiglu-pack -> h [32768][4096]
    gemm8ph<D_DIM, 1><<<dim3((M/256) * (2*F_DIM/256)), 512, 0, stream>>>(flat, wc, nullptr, h, 2*F_DIM);
    // GEMM2: [32768][4096] x [1024][4096]^T + x -> out [32768][1024]
    gemm8ph<F_DIM, 0><<<dim3((M/256) * (D_DIM/256)), 512, 0, stream>>>(h, wdt, x, out, D_DIM);
}

// Round 12
// 823.367 us; speedup vs baseline: 1.2223x; 1.2223x over previous
//
#include <hip/hip_runtime.h>

typedef unsigned short u16;
using bf16x8 = __attribute__((ext_vector_type(8))) __bf16;
using f32x4  = __attribute__((ext_vector_type(4))) float;
using u16x4  = __attribute__((ext_vector_type(4))) unsigned short;

#define D_DIM 1024
#define F_DIM 4096

// ---------------- Cayley table (Cl(3,0)), compile-time ----------------
struct Cayley { int k[8][8]; int s[8][8]; };
constexpr Cayley make_cayley() {
    Cayley c{};
    const int gens[8][3] = {{0,0,0},{1,0,0},{2,0,0},{3,0,0},{1,2,0},{1,3,0},{2,3,0},{1,2,3}};
    const int glen[8] = {0,1,1,1,2,2,2,3};
    const int mask2idx[8] = {0,1,2,4,3,5,6,7};
    for (int i = 0; i < 8; ++i) {
        for (int j = 0; j < 8; ++j) {
            int g[6] = {0,0,0,0,0,0};
            int n = 0;
            for (int t = 0; t < glen[i]; ++t) g[n++] = gens[i][t];
            for (int t = 0; t < glen[j]; ++t) g[n++] = gens[j][t];
            int sign = 1;
            bool changed = true;
            while (changed) {
                changed = false;
                int t = 0;
                while (t + 1 < n) {
                    if (g[t] == g[t+1]) {
                        for (int u = t; u + 2 < n; ++u) g[u] = g[u+2];
                        n -= 2; changed = true;
                        if (t > 0) --t;
                    } else if (g[t] > g[t+1]) {
                        int tmp = g[t]; g[t] = g[t+1]; g[t+1] = tmp;
                        sign = -sign; changed = true; ++t;
                    } else {
                        ++t;
                    }
                }
            }
            int mask = 0;
            for (int t = 0; t < n; ++t) mask |= 1 << (g[t] - 1);
            c.k[i][j] = mask2idx[mask];
            c.s[i][j] = sign;
        }
    }
    return c;
}
constexpr Cayley CAY = make_cayley();

// ---------------- helpers ----------------
__device__ __forceinline__ u16 f2bf(float f) {           // RNE f32->bf16
    unsigned u = __float_as_uint(f);
    unsigned r = 0x7FFFu + ((u >> 16) & 1u);
    return (u16)((u + r) >> 16);
}

__device__ __forceinline__ void gload16(const u16* g, const u16* l) {
    __builtin_amdgcn_global_load_lds(
        (const __attribute__((address_space(1))) void*)g,
        (__attribute__((address_space(3))) void*)l, 16, 0, 0);
}

// swizzled LDS fragment read: tile is [256][64] u16, row-linear with slot^=(row&7)
__device__ __forceinline__ bf16x8 frag(const u16* tile, int row, int ks, int lane) {
    const int slot = ((ks << 2) + (lane >> 4)) ^ (lane & 7);
    return *(const bf16x8*)(tile + row * 64 + slot * 8);
}

// ---------------- weight transpose f32 [R][C] -> bf16 [C][R], with optional
// gate/up chunk interleave: mode 0 plain, 1 gate (16-col chunks even), 2 up (odd) ----
__global__ __launch_bounds__(256) void transpose_kernel(
    const float* __restrict__ in, u16* __restrict__ outp, int R, int C, int mode)
{
    __shared__ float tile[32][33];
    const int tx = threadIdx.x & 31, ty = threadIdx.x >> 5;
    const int c0 = blockIdx.x * 32, r0 = blockIdx.y * 32;
    #pragma unroll
    for (int t = 0; t < 4; ++t)
        tile[ty + t*8][tx] = in[(size_t)(r0 + ty + t*8) * C + c0 + tx];
    __syncthreads();
    #pragma unroll
    for (int t = 0; t < 4; ++t) {
        const int c = c0 + ty + t*8;
        int orow;
        if (mode == 0)      orow = c;
        else if (mode == 1) orow = ((c >> 4) << 5) + (c & 15);
        else                orow = ((c >> 4) << 5) + 16 + (c & 15);
        outp[(size_t)orow * R + r0 + tx] = f2bf(tile[tx][ty + t*8]);
    }
}

// ---------------- fused geometric product + mix + LayerNorm -> bf16 flat ----------------
__global__ __launch_bounds__(256, 2) void geo_ln_kernel(
    const float* __restrict__ x, const float* __restrict__ iw,
    const float* __restrict__ gg, const float* __restrict__ lnw,
    const float* __restrict__ lnb, u16* __restrict__ flat)
{
    __shared__ float wsig[64];
    __shared__ float red[4][16];
    const int tid = threadIdx.x;
    if (tid < 64) wsig[tid] = 1.f / (1.f + __expf(-iw[tid]));
    __syncthreads();
    const float g   = 1.f / (1.f + __expf(-gg[0]));
    const float gm1 = 1.f - g;

    float coef[64];
    #pragma unroll
    for (int t = 0; t < 64; ++t) coef[t] = (float)CAY.s[t >> 3][t & 7] * wsig[t];

    const int n  = blockIdx.x;
    const int d0 = tid * 4;
    const float* xb = x + (size_t)n * 8 * D_DIM;
    f32x4 xv[8];
    #pragma unroll
    for (int i = 0; i < 8; ++i) xv[i] = __builtin_nontemporal_load((const f32x4*)(xb + i * D_DIM + d0));

    float mix[8][4];
    #pragma unroll
    for (int s4 = 0; s4 < 4; ++s4) {
        float xs[8];
        #pragma unroll
        for (int i = 0; i < 8; ++i) xs[i] = xv[i][s4];
        float geo[8] = {0.f,0.f,0.f,0.f,0.f,0.f,0.f,0.f};
        #pragma unroll
        for (int i = 0; i < 8; ++i) {
            #pragma unroll
            for (int j = 0; j < 8; ++j) {
                geo[CAY.k[i][j]] = fmaf(coef[i*8+j] * xs[i], xs[j], geo[CAY.k[i][j]]);
            }
        }
        #pragma unroll
        for (int k = 0; k < 8; ++k) mix[k][s4] = g * geo[k] + gm1 * xs[k];
    }

    float s1[8], s2[8];
    #pragma unroll
    for (int k = 0; k < 8; ++k) {
        s1[k] = 0.f; s2[k] = 0.f;
        #pragma unroll
        for (int s4 = 0; s4 < 4; ++s4) {
            s1[k] += mix[k][s4];
            s2[k]  = fmaf(mix[k][s4], mix[k][s4], s2[k]);
        }
    }
    #pragma unroll
    for (int m = 1; m < 64; m <<= 1) {
        #pragma unroll
        for (int k = 0; k < 8; ++k) {
            s1[k] += __shfl_xor(s1[k], m, 64);
            s2[k] += __shfl_xor(s2[k], m, 64);
        }
    }
    const int wave = tid >> 6, lane = tid & 63;
    if (lane == 0) {
        #pragma unroll
        for (int k = 0; k < 8; ++k) { red[wave][k] = s1[k]; red[wave][8+k] = s2[k]; }
    }
    __syncthreads();
    float mean[8], rstd[8];
    #pragma unroll
    for (int k = 0; k < 8; ++k) {
        float a = red[0][k] + red[1][k] + red[2][k] + red[3][k];
        float b = red[0][8+k] + red[1][8+k] + red[2][8+k] + red[3][8+k];
        float mu  = a * (1.f / 1024.f);
        float var = b * (1.f / 1024.f) - mu * mu;
        mean[k] = mu;
        rstd[k] = rsqrtf(var + 1e-5f);
    }
    f32x4 lw = *(const f32x4*)(lnw + d0);
    f32x4 lb = *(const f32x4*)(lnb + d0);
    #pragma unroll
    for (int k = 0; k < 8; ++k) {
        u16x4 o;
        #pragma unroll
        for (int s4 = 0; s4 < 4; ++s4) {
            float v = (mix[k][s4] - mean[k]) * rstd[k] * lw[s4] + lb[s4];
            o[s4] = f2bf(v);
        }
        *(u16x4*)(flat + ((size_t)(n * 8 + k)) * D_DIM + d0) = o;
    }
}

// ================= 256x256 8-wave pipelined GEMM, 2 phases/K-step =================
// A [M][KDIM] bf16, B [N][KDIM] bf16 (B^T). EPI=1: swiglu-pack -> h bf16 (nt).
// EPI=0: out = X + acc, f32 (nt).
// 2-phase single-barrier schedule (round-8 structure) with SYMMETRIC vmcnt(8)
// ledger (fixed point F=8 in flight at every phase boundary; all loads get
// 2-phase issue-to-wait slack):
//  phA(t): reads A-half0(8)+bf0(4)+bf1(4); stage A1(t+1),B1(t+1) -> nbuf[128..]
//          (nbuf unread during step t); 32 MFMA; vmcnt(8) retires phA(t-1)'s
//          A1/B1(t) exactly at its deadline (phB(t) start); barrier.
//  phB(t): reads A-half1(8) (bf0/bf1 register-resident; Bs[buf] dead after phA);
//          stage A0(t+2),B0(t+2) -> buf[0..127] (half0 dead after phA barrier);
//          32 MFMA; vmcnt(8) retires phB(t-1)'s A0/B0(t+1) at deadline
//          (phA(t+1) start); barrier.
// Prologue: A0,B0,A1,B1(0),A0,B0(1) = 12 loads; vmcnt(4) retires the 8 oldest
// (everything tile-0 needs) keeping A0/B0(1) in flight.
// Tail: t=NT-2 <WA=8,WB=4> (phB keeps A1/B1(NT-1) in flight);
//       t=NT-1 <WA=0> (drains A1/B1(NT-1) before phB reads), no phB wait.
template<int KDIM, bool S1, bool S2, int WA, int WB>
__device__ __forceinline__ void ktile2(
    int t, const u16* __restrict__ A, const u16* __restrict__ B,
    u16 (*As)[256][64], u16 (*Bs)[256][64],
    int brow, int bcol, int wave, int lane, int wm, int wn, int fr,
    f32x4 (&acc)[8][4])
{
    const int buf = t & 1;
    const int nbuf = (t + 1) & 1;
    const u16* At = &As[buf][0][0];
    const u16* Bt = &Bs[buf][0][0];
    const int sr = lane >> 3, sslot = (lane & 7) ^ sr;

    bf16x8 af[4][2], bf0[2][2], bf1[2][2];

    // ======== phase A: quadrants (0,0),(0,1) ========
    #pragma unroll
    for (int m = 0; m < 4; ++m)
        #pragma unroll
        for (int ks = 0; ks < 2; ++ks)
            af[m][ks] = frag(At, wm*64 + m*16 + fr, ks, lane);
    #pragma unroll
    for (int n = 0; n < 2; ++n)
        #pragma unroll
        for (int ks = 0; ks < 2; ++ks) {
            bf0[n][ks] = frag(Bt, wn*32 + n*16 + fr, ks, lane);
            bf1[n][ks] = frag(Bt, 128 + wn*32 + n*16 + fr, ks, lane);
        }
    if (S1) {
        #pragma unroll
        for (int q = 0; q < 2; ++q) {
            const int idx_w = q*512 + wave*64;
            const int row = (idx_w >> 3) + sr;
            gload16(A + (size_t)(brow + 128 + row)*KDIM + (t+1)*64 + sslot*8,
                    &As[nbuf][128][0] + idx_w*8);
        }
        #pragma unroll
        for (int q = 0; q < 2; ++q) {
            const int idx_w = q*512 + wave*64;
            const int row = (idx_w >> 3) + sr;
            gload16(B + (size_t)(bcol + 128 + row)*KDIM + (t+1)*64 + sslot*8,
                    &Bs[nbuf][128][0] + idx_w*8);
        }
    }
    __builtin_amdgcn_s_setprio(1);
    #pragma unroll
    for (int m = 0; m < 4; ++m)
        #pragma unroll
        for (int n = 0; n < 2; ++n)
            #pragma unroll
            for (int ks = 0; ks < 2; ++ks) {
                acc[m][n]   = __builtin_amdgcn_mfma_f32_16x16x32_bf16(af[m][ks], bf0[n][ks], acc[m][n],   0, 0, 0);
                acc[m][2+n] = __builtin_amdgcn_mfma_f32_16x16x32_bf16(af[m][ks], bf1[n][ks], acc[m][2+n], 0, 0, 0);
            }
    __builtin_amdgcn_s_setprio(0);
    if constexpr (WA == 8)      asm volatile("s_waitcnt vmcnt(8)" ::: "memory");
    else if constexpr (WA == 0) asm volatile("s_waitcnt vmcnt(0)" ::: "memory");
    __builtin_amdgcn_s_barrier();
    __builtin_amdgcn_sched_barrier(0);

    // ======== phase B: quadrants (1,0),(1,1) ========
    #pragma unroll
    for (int m = 0; m < 4; ++m)
        #pragma unroll
        for (int ks = 0; ks < 2; ++ks)
            af[m][ks] = frag(At, 128 + wm*64 + m*16 + fr, ks, lane);
    if (S2) {
        #pragma unroll
        for (int q = 0; q < 2; ++q) {
            const int idx_w = q*512 + wave*64;
            const int row = (idx_w >> 3) + sr;
            gload16(A + (size_t)(brow + row)*KDIM + (t+2)*64 + sslot*8,
                    &As[buf][0][0] + idx_w*8);
        }
        #pragma unroll
        for (int q = 0; q < 2; ++q) {
            const int idx_w = q*512 + wave*64;
            const int row = (idx_w >> 3) + sr;
            gload16(B + (size_t)(bcol + row)*KDIM + (t+2)*64 + sslot*8,
                    &Bs[buf][0][0] + idx_w*8);
        }
    }
    __builtin_amdgcn_s_setprio(1);
    #pragma unroll
    for (int m = 0; m < 4; ++m)
        #pragma unroll
        for (int n = 0; n < 2; ++n)
            #pragma unroll
            for (int ks = 0; ks < 2; ++ks) {
                acc[4+m][n]   = __builtin_amdgcn_mfma_f32_16x16x32_bf16(af[m][ks], bf0[n][ks], acc[4+m][n],   0, 0, 0);
                acc[4+m][2+n] = __builtin_amdgcn_mfma_f32_16x16x32_bf16(af[m][ks], bf1[n][ks], acc[4+m][2+n], 0, 0, 0);
            }
    __builtin_amdgcn_s_setprio(0);
    if constexpr (WB == 8)      asm volatile("s_waitcnt vmcnt(8)" ::: "memory");
    else if constexpr (WB == 4) asm volatile("s_waitcnt vmcnt(4)" ::: "memory");
    __builtin_amdgcn_s_barrier();
    __builtin_amdgcn_sched_barrier(0);
}

template<int KDIM, int EPI>
__global__ __launch_bounds__(512, 2) void gemm8ph(
    const u16* __restrict__ A, const u16* __restrict__ B,
    const float* __restrict__ X, void* __restrict__ OUT, int Ncols)
{
    constexpr int NT = KDIM / 64;
    __shared__ alignas(16) u16 As[2][256][64];
    __shared__ alignas(16) u16 Bs[2][256][64];

    const int nbx = Ncols >> 8;
    const int nwg = gridDim.x;
    const int bid = blockIdx.x;
    int brow, bcol;
    if constexpr (EPI == 1) {
        // XCD column-strip (round-5 best for GEMM1): each XCD owns nbx/8 cols;
        // its B strip (4 cols x 256 x 1024 x 2B = 2 MiB) stays L2-resident.
        const int xcd = bid & 7, idx = bid >> 3;
        const int cpx = nbx >> 3;
        bcol = (xcd * cpx + (idx & (cpx - 1))) << 8;
        brow = (idx / cpx) << 8;
    } else {
        // standard XCD swizzle (round-4 best for GEMM2)
        const int wg = (bid & 7) * (nwg >> 3) + (bid >> 3);
        brow = (wg / nbx) << 8;
        bcol = (wg % nbx) << 8;
    }

    const int tid = threadIdx.x;
    const int wave = tid >> 6, lane = tid & 63;
    const int wm = wave >> 2, wn = wave & 3;
    const int fr = lane & 15, fq = lane >> 4;
    const int sr = lane >> 3, sslot = (lane & 7) ^ sr;

    f32x4 acc[8][4];
    #pragma unroll
    for (int i = 0; i < 8; ++i)
        #pragma unroll
        for (int j = 0; j < 4; ++j) acc[i][j] = {0.f, 0.f, 0.f, 0.f};

    // ---- prologue: stage A0(0),B0(0),A1(0),B1(0),A0(1),B0(1) ----
    #pragma unroll
    for (int q = 0; q < 2; ++q) {
        const int idx_w = q*512 + wave*64;
        const int row = (idx_w >> 3) + sr;
        gload16(A + (size_t)(brow + row)*KDIM + sslot*8,          &As[0][0][0]   + idx_w*8);
    }
    #pragma unroll
    for (int q = 0; q < 2; ++q) {
        const int idx_w = q*512 + wave*64;
        const int row = (idx_w >> 3) + sr;
        gload16(B + (size_t)(bcol + row)*KDIM + sslot*8,          &Bs[0][0][0]   + idx_w*8);
    }
    #pragma unroll
    for (int q = 0; q < 2; ++q) {
        const int idx_w = q*512 + wave*64;
        const int row = (idx_w >> 3) + sr;
        gload16(A + (size_t)(brow + 128 + row)*KDIM + sslot*8,    &As[0][128][0] + idx_w*8);
    }
    #pragma unroll
    for (int q = 0; q < 2; ++q) {
        const int idx_w = q*512 + wave*64;
        const int row = (idx_w >> 3) + sr;
        gload16(B + (size_t)(bcol + 128 + row)*KDIM + sslot*8,    &Bs[0][128][0] + idx_w*8);
    }
    #pragma unroll
    for (int q = 0; q < 2; ++q) {
        const int idx_w = q*512 + wave*64;
        const int row = (idx_w >> 3) + sr;
        gload16(A + (size_t)(brow + row)*KDIM + 64 + sslot*8,     &As[1][0][0]   + idx_w*8);
    }
    #pragma unroll
    for (int q = 0; q < 2; ++q) {
        const int idx_w = q*512 + wave*64;
        const int row = (idx_w >> 3) + sr;
        gload16(B + (size_t)(bcol + row)*KDIM + 64 + sslot*8,     &Bs[1][0][0]   + idx_w*8);
    }
    asm volatile("s_waitcnt vmcnt(4)" ::: "memory");  // retire 8 oldest: all tile-0 data
    __builtin_amdgcn_s_barrier();
    __builtin_amdgcn_sched_barrier(0);

    // ---- main loop ----
    #pragma unroll 1
    for (int t = 0; t < NT - 2; ++t)
        ktile2<KDIM, true, true, 8, 8>(t, A, B, As, Bs, brow, bcol, wave, lane, wm, wn, fr, acc);
    ktile2<KDIM, true,  false, 8, 4>(NT-2, A, B, As, Bs, brow, bcol, wave, lane, wm, wn, fr, acc);
    ktile2<KDIM, false, false, 0, -1>(NT-1, A, B, As, Bs, brow, bcol, wave, lane, wm, wn, fr, acc);

    // ---- epilogue (nontemporal stream-out) ----
    if constexpr (EPI == 1) {
        u16* H = (u16*)OUT;
        const int Nh = Ncols >> 1;
        #pragma unroll
        for (int qm = 0; qm < 2; ++qm)
            #pragma unroll
            for (int m = 0; m < 4; ++m) {
                const int row = brow + qm*128 + wm*64 + m*16 + fq*4;
                #pragma unroll
                for (int qn = 0; qn < 2; ++qn) {
                    const int col = (bcol >> 1) + qn*64 + wn*16 + fr;
                    f32x4 g = acc[qm*4+m][qn*2+0];
                    f32x4 u = acc[qm*4+m][qn*2+1];
                    #pragma unroll
                    for (int r = 0; r < 4; ++r) {
                        float gv = g[r], uv = u[r];
                        float hv = (gv / (1.f + __expf(-gv))) * uv;
                        __builtin_nontemporal_store(f2bf(hv), &H[(size_t)(row + r) * Nh + col]);
                    }
                }
            }
    } else {
        float* Of = (float*)OUT;
        #pragma unroll
        for (int mi = 0; mi < 8; ++mi) {
            const int row = brow + (mi>>2)*128 + wm*64 + (mi&3)*16 + fq*4;
            #pragma unroll
            for (int ni = 0; ni < 4; ++ni) {
                const int col = bcol + (ni>>1)*128 + wn*32 + (ni&1)*16 + fr;
                #pragma unroll
                for (int r = 0; r < 4; ++r) {
                    float xv = __builtin_nontemporal_load(&X[(size_t)(row+r)*Ncols + col]);
                    __builtin_nontemporal_store(xv + acc[mi][ni][r], &Of[(size_t)(row+r)*Ncols + col]);
                }
            }
        }
    }
}

// ---------------- launch ----------------
extern "C" void kernel_launch(void* const* d_in, const int* in_sizes, int n_in,
                              void* d_out, int out_size, void* d_ws, size_t ws_size,
                              hipStream_t stream) {
    const float* x     = (const float*)d_in[0];
    const float* iw    = (const float*)d_in[1];
    const float* gg    = (const float*)d_in[2];
    const float* lnw   = (const float*)d_in[3];
    const float* lnb   = (const float*)d_in[4];
    const float* wgate = (const float*)d_in[5];
    const float* wup   = (const float*)d_in[6];
    const float* wdown = (const float*)d_in[7];
    float* out = (float*)d_out;

    const int ntok = in_sizes[0] / (8 * D_DIM);   // 4096
    const int M    = ntok * 8;                    // 32768

    const size_t flat_b = (size_t)M * D_DIM * 2;          //  64 MiB
    const size_t wc_b   = (size_t)2 * D_DIM * F_DIM * 2;  //  16 MiB (combined gate+up)
    const size_t wd_b   = (size_t)D_DIM * F_DIM * 2;      //   8 MiB
    const size_t h_b    = (size_t)M * F_DIM * 2;          // 256 MiB
    const size_t need   = flat_b + wc_b + wd_b + h_b;
    if (ws_size < need) return;

    char* ws = (char*)d_ws;
    u16* flat = (u16*)(ws);
    u16* wc   = (u16*)(ws + flat_b);
    u16* wdt  = (u16*)(ws + flat_b + wc_b);
    u16* h    = (u16*)(ws + flat_b + wc_b + wd_b);

    transpose_kernel<<<dim3(F_DIM/32, D_DIM/32), 256, 0, stream>>>(wgate, wc,  D_DIM, F_DIM, 1);
    transpose_kernel<<<dim3(F_DIM/32, D_DIM/32), 256, 0, stream>>>(wup,   wc,  D_DIM, F_DIM, 2);
    transpose_kernel<<<dim3(D_DIM/32, F_DIM/32), 256, 0, stream>>>(wdown, wdt, F_DIM, D_DIM, 0);
    geo_ln_kernel<<<dim3(ntok), 256, 0, stream>>>(x, iw, gg, lnw, lnb, flat);

    // GEMM1: [32768][1024] x [8192][1024]^T -> swiglu-pack -> h [32768][4096]
    gemm8ph<D_DIM, 1><<<dim3((M/256) * (2*F_DIM/256)), 512, 0, stream>>>(flat, wc, nullptr, h, 2*F_DIM);
    // GEMM2: [32768][4096] x [1024][4096]^T + x -> out [32768][1024]
    gemm8ph<F_DIM, 0><<<dim3((M/256) * (D_DIM/256)), 512, 0, stream>>>(h, wdt, x, out, D_DIM);
}